// Round 5
// baseline (2908.624 us; speedup 1.0000x reference)
//
#include <hip/hip_runtime.h>
#include <hip/hip_bf16.h>
#include <math.h>

// ---------------- problem constants ----------------
constexpr int T_STEPS = 256;
constexpr int HDIM    = 1024;
constexpr int EDIM    = 512;
constexpr int VDIM    = 32000;

#define RG     128          // recurrence workgroups (spread over chip, 1/CU)
#define RROWS  8            // rows owned per WG (2 per wave)

// ---------------- ws layout (float offsets) ----------------
// Overlays (safety re-proven under wave-granular skew <= 1 step):
//  - hseq fp32 [T][H] overlays BZ  (write of row i at step t follows the owner's own Bz[t][i] read)
//  - hseq bf16 [T][H] overlays BR  (write at step t touches Br[t/2]; all waves are past step t-1 > t/2)
constexpr size_t WS_BZ     = 0;                                   // [T][H]
constexpr size_t WS_BR     = WS_BZ + (size_t)T_STEPS * HDIM;      // [T][H]
constexpr size_t WS_A      = WS_BR + (size_t)T_STEPS * HDIM;      // [T][H]
constexpr size_t WS_HPACK  = WS_A  + (size_t)T_STEPS * HDIM;      // ull[(T+1)][H]: (tag<<32)|bits
constexpr size_t WS_RHPACK = WS_HPACK + (size_t)2 * (T_STEPS + 1) * HDIM; // ull[H]
constexpr size_t WS_HSEQ   = WS_BZ;                               // fp32 overlay
constexpr size_t WS_HSEQB  = WS_BR;                               // bf16 overlay (ushort*)

typedef __attribute__((ext_vector_type(8))) short short8;
typedef __attribute__((ext_vector_type(4))) float f32x4;

__device__ __forceinline__ float sigmoidf_(float x) { return 1.0f / (1.0f + __expf(-x)); }

__device__ __forceinline__ unsigned long long pack_tv(int tag, float v) {
  return ((unsigned long long)(unsigned)tag << 32) | (unsigned long long)__float_as_uint(v);
}

__device__ __forceinline__ unsigned short f2bf(float f) {   // RNE fp32 -> bf16 bits
  unsigned u = __float_as_uint(f);
  return (unsigned short)((u + 0x7FFFu + ((u >> 16) & 1u)) >> 16);
}

// ---------------- init: clear tags (ws NOT re-poisoned between replays), pack h0 ----------------
__global__ __launch_bounds__(256) void k_init(const float* __restrict__ enc, float* __restrict__ ws) {
  unsigned long long* hpack  = (unsigned long long*)(ws + WS_HPACK);
  unsigned long long* rhpack = (unsigned long long*)(ws + WS_RHPACK);
  const int b = blockIdx.x, tid = threadIdx.x;
  if (b == 0) {
    for (int i = tid; i < HDIM; i += 256) hpack[i] = pack_tv(1, enc[i]);
  } else if (b <= T_STEPS) {
    unsigned long long* row = hpack + (size_t)b * HDIM;
    for (int i = tid; i < HDIM; i += 256) row[i] = 0ULL;
  } else {
    for (int i = tid; i < HDIM; i += 256) rhpack[i] = 0ULL;
  }
}

// ---------------- batched e-projections: Bz/Br/A for all t ----------------
__global__ __launch_bounds__(256) void k_xproj(
    const int* __restrict__ tokens, const float* __restrict__ emb,
    const float* __restrict__ wzx, const float* __restrict__ wrx, const float* __restrict__ whx,
    const float* __restrict__ bzx, const float* __restrict__ bzh,
    const float* __restrict__ brx, const float* __restrict__ brh,
    const float* __restrict__ bhx, const float* __restrict__ bhh,
    float* __restrict__ ws) {
  __shared__ __align__(16) float es[16][EDIM];   // 32 KiB
  const int b   = blockIdx.x;
  const int t0  = (b & 15) * 16;
  const int c   = b >> 4;                 // 0..11
  const int tid = threadIdx.x;

  {
    int row = tid >> 4;
    int kc  = (tid & 15) * 32;
    int tok = tokens[t0 + row];
    const float4* ep = (const float4*)(emb + (size_t)tok * EDIM + kc);
    float4* dst = (float4*)&es[row][kc];
    #pragma unroll
    for (int q = 0; q < 8; q++) dst[q] = ep[q];
  }
  __syncthreads();

  const int mat = c >> 2;
  const int j   = (c & 3) * 256 + tid;
  const float* W; const float* b1; const float* b2; float* Xout;
  if (mat == 0)      { W = wzx; b1 = bzx; b2 = bzh; Xout = ws + WS_BZ; }
  else if (mat == 1) { W = wrx; b1 = brx; b2 = brh; Xout = ws + WS_BR; }
  else               { W = whx; b1 = bhx; b2 = bhh; Xout = ws + WS_A;  }

  const float4* wp = (const float4*)(W + (size_t)j * EDIM);
  const float bias = b1[j] + b2[j];
  float acc[16];
  #pragma unroll
  for (int tt = 0; tt < 16; tt++) acc[tt] = 0.0f;

  for (int k4 = 0; k4 < EDIM / 4; k4++) {
    float4 w = wp[k4];
    #pragma unroll
    for (int tt = 0; tt < 16; tt++) {
      float4 e4 = *(const float4*)&es[tt][k4 * 4];
      acc[tt] += w.x * e4.x + w.y * e4.y + w.z * e4.z + w.w * e4.w;
    }
  }
  #pragma unroll
  for (int tt = 0; tt < 16; tt++)
    Xout[(size_t)(t0 + tt) * HDIM + j] = acc[tt] + bias;
}

// ---------------- persistent GRU recurrence: per-wave rows, no LDS, no barriers ----------------
// 128 WGs x 4 waves; wave wv owns rows {g*8+2wv, +1}. Lane l covers cols {4l+256q, q=0..3}.
// Row reductions are pure 64-lane shfl_xor; each wave publishes independently (agent atomics).
// Weight loads are issued BEFORE each poll so L2 latency hides under the IC round-trip.
__global__ __launch_bounds__(256) void k_recur(
    const float* __restrict__ wzh, const float* __restrict__ wrh, const float* __restrict__ whh,
    float* __restrict__ ws) {
  const int g    = blockIdx.x;
  const int tid  = threadIdx.x;
  const int lane = tid & 63;
  const int wv   = tid >> 6;
  const int row0 = g * RROWS + 2 * wv;
  const int row1 = row0 + 1;

  const float* Bz = ws + WS_BZ;
  const float* Br = ws + WS_BR;
  const float* Aa = ws + WS_A;
  float* hseq = ws + WS_HSEQ;
  unsigned short* hseqb = (unsigned short*)(ws + WS_HSEQB);
  unsigned long long* hpack  = (unsigned long long*)(ws + WS_HPACK);
  unsigned long long* rhpack = (unsigned long long*)(ws + WS_RHPACK);

  const int c0 = 4 * lane;

  // h for own rows, kept wave-uniform in registers (written by k_init)
  float hl0 = __uint_as_float((unsigned)hpack[row0]);
  float hl1 = __uint_as_float((unsigned)hpack[row1]);

  for (int t = 0; t < T_STEPS; t++) {
    const unsigned long long ex = (unsigned long long)(unsigned)(t + 1);

    // uniform per-step constants (same addr across lanes -> broadcast)
    float br0 = Br[(size_t)t * HDIM + row0], br1 = Br[(size_t)t * HDIM + row1];
    float bz0 = Bz[(size_t)t * HDIM + row0], bz1 = Bz[(size_t)t * HDIM + row1];
    float a0  = Aa[(size_t)t * HDIM + row0], a1  = Aa[(size_t)t * HDIM + row1];

    // ---- round-A weights: issue before the h poll (independent of polled data) ----
    float4 WZ0[4], WZ1[4], WR0[4], WR1[4];
    #pragma unroll
    for (int q = 0; q < 4; q++) {
      const int col = c0 + 256 * q;
      WZ0[q] = *(const float4*)(wzh + (size_t)row0 * HDIM + col);
      WZ1[q] = *(const float4*)(wzh + (size_t)row1 * HDIM + col);
      WR0[q] = *(const float4*)(wrh + (size_t)row0 * HDIM + col);
      WR1[q] = *(const float4*)(wrh + (size_t)row1 * HDIM + col);
    }

    // ---- poll h_t: 16 words per lane, all loads pipelined per iteration ----
    unsigned long long hw[16];
    {
      const unsigned long long* hp = hpack + (size_t)t * HDIM;
      int it = 0;
      for (;;) {
        #pragma unroll
        for (int q = 0; q < 4; q++)
          #pragma unroll
          for (int c = 0; c < 4; c++)
            hw[q * 4 + c] = __hip_atomic_load(hp + c0 + 256 * q + c,
                                              __ATOMIC_RELAXED, __HIP_MEMORY_SCOPE_AGENT);
        bool ok = true;
        #pragma unroll
        for (int i = 0; i < 16; i++) ok &= ((hw[i] >> 32) == ex);
        if (ok) break;
        if (++it > (1 << 14)) break;   // bounded failure, never hang
        __builtin_amdgcn_s_sleep(1);
      }
    }

    float accz0 = 0.f, accz1 = 0.f, accr0 = 0.f, accr1 = 0.f;
    #pragma unroll
    for (int q = 0; q < 4; q++) {
      const float h0 = __uint_as_float((unsigned)hw[q * 4 + 0]);
      const float h1 = __uint_as_float((unsigned)hw[q * 4 + 1]);
      const float h2 = __uint_as_float((unsigned)hw[q * 4 + 2]);
      const float h3 = __uint_as_float((unsigned)hw[q * 4 + 3]);
      accr0 += WR0[q].x * h0 + WR0[q].y * h1 + WR0[q].z * h2 + WR0[q].w * h3;
      accr1 += WR1[q].x * h0 + WR1[q].y * h1 + WR1[q].z * h2 + WR1[q].w * h3;
      accz0 += WZ0[q].x * h0 + WZ0[q].y * h1 + WZ0[q].z * h2 + WZ0[q].w * h3;
      accz1 += WZ1[q].x * h0 + WZ1[q].y * h1 + WZ1[q].z * h2 + WZ1[q].w * h3;
    }

    // ---- round-B weights: issue now, latency hides under reduce + rh hop ----
    float4 WH0[4], WH1[4];
    #pragma unroll
    for (int q = 0; q < 4; q++) {
      const int col = c0 + 256 * q;
      WH0[q] = *(const float4*)(whh + (size_t)row0 * HDIM + col);
      WH1[q] = *(const float4*)(whh + (size_t)row1 * HDIM + col);
    }

    // r first: publish rh as early as possible (z reduce happens after the publish)
    #pragma unroll
    for (int m = 32; m >= 1; m >>= 1) {
      accr0 += __shfl_xor(accr0, m);
      accr1 += __shfl_xor(accr1, m);
    }
    const float r0 = sigmoidf_(br0 + accr0);
    const float r1 = sigmoidf_(br1 + accr1);
    if (lane == 0) {
      __hip_atomic_store(&rhpack[row0], pack_tv(t + 1, r0 * hl0),
                         __ATOMIC_RELAXED, __HIP_MEMORY_SCOPE_AGENT);
      __hip_atomic_store(&rhpack[row1], pack_tv(t + 1, r1 * hl1),
                         __ATOMIC_RELAXED, __HIP_MEMORY_SCOPE_AGENT);
    }
    #pragma unroll
    for (int m = 32; m >= 1; m >>= 1) {
      accz0 += __shfl_xor(accz0, m);
      accz1 += __shfl_xor(accz1, m);
    }
    const float z0 = sigmoidf_(bz0 + accz0);
    const float z1 = sigmoidf_(bz1 + accz1);

    // ---- poll rh: 16 words ----
    unsigned long long rw[16];
    {
      int it = 0;
      for (;;) {
        #pragma unroll
        for (int q = 0; q < 4; q++)
          #pragma unroll
          for (int c = 0; c < 4; c++)
            rw[q * 4 + c] = __hip_atomic_load(rhpack + c0 + 256 * q + c,
                                              __ATOMIC_RELAXED, __HIP_MEMORY_SCOPE_AGENT);
        bool ok = true;
        #pragma unroll
        for (int i = 0; i < 16; i++) ok &= ((rw[i] >> 32) == ex);
        if (ok) break;
        if (++it > (1 << 14)) break;
        __builtin_amdgcn_s_sleep(1);
      }
    }

    float accv0 = 0.f, accv1 = 0.f;
    #pragma unroll
    for (int q = 0; q < 4; q++) {
      const float v0 = __uint_as_float((unsigned)rw[q * 4 + 0]);
      const float v1 = __uint_as_float((unsigned)rw[q * 4 + 1]);
      const float v2 = __uint_as_float((unsigned)rw[q * 4 + 2]);
      const float v3 = __uint_as_float((unsigned)rw[q * 4 + 3]);
      accv0 += WH0[q].x * v0 + WH0[q].y * v1 + WH0[q].z * v2 + WH0[q].w * v3;
      accv1 += WH1[q].x * v0 + WH1[q].y * v1 + WH1[q].z * v2 + WH1[q].w * v3;
    }
    #pragma unroll
    for (int m = 32; m >= 1; m >>= 1) {
      accv0 += __shfl_xor(accv0, m);
      accv1 += __shfl_xor(accv1, m);
    }
    const float hp0 = tanhf(a0 + accv0);
    const float hp1 = tanhf(a1 + accv1);
    const float hn0 = (1.0f - z0) * hl0 + z0 * hp0;
    const float hn1 = (1.0f - z1) * hl1 + z1 * hp1;
    hl0 = hn0; hl1 = hn1;

    if (lane == 0) {
      __hip_atomic_store(&hpack[(size_t)(t + 1) * HDIM + row0], pack_tv(t + 2, hn0),
                         __ATOMIC_RELAXED, __HIP_MEMORY_SCOPE_AGENT);
      __hip_atomic_store(&hpack[(size_t)(t + 1) * HDIM + row1], pack_tv(t + 2, hn1),
                         __ATOMIC_RELAXED, __HIP_MEMORY_SCOPE_AGENT);
      *(float2*)(hseq + (size_t)t * HDIM + row0) = make_float2(hn0, hn1);   // fp32 (refine)
      unsigned pk = (unsigned)f2bf(hn0) | ((unsigned)f2bf(hn1) << 16);
      *(unsigned*)(hseqb + (size_t)t * HDIM + row0) = pk;                   // bf16 (GEMM A)
    }
  }
}

// ---------------- logits GEMM (bf16 MFMA): [256,1024] @ out_w[32000,1024]^T + out_b ----------------
__global__ __launch_bounds__(256) void k_gemm(
    const unsigned short* __restrict__ Abf, const float* __restrict__ outw,
    const float* __restrict__ outb, float* __restrict__ out) {
  const int tid  = threadIdx.x;
  const int lane = tid & 63;
  const int wv   = tid >> 6;
  const int n0   = blockIdx.x * 128;
  const int rA   = lane & 15;
  const int kg   = lane >> 4;

  f32x4 acc[4][8];
  #pragma unroll
  for (int i = 0; i < 4; i++)
    #pragma unroll
    for (int j = 0; j < 8; j++) acc[i][j] = (f32x4){0.f, 0.f, 0.f, 0.f};

  const int mbase = wv * 64 + rA;

  for (int k0 = 0; k0 < HDIM; k0 += 32) {
    const int ks = k0 + kg * 8;
    short8 afr[4];
    #pragma unroll
    for (int i = 0; i < 4; i++)
      afr[i] = *(const short8*)(Abf + (size_t)(mbase + i * 16) * HDIM + ks);

    short8 bfr[8];
    #pragma unroll
    for (int j = 0; j < 8; j++) {
      const float* bp = outw + (size_t)(n0 + j * 16 + rA) * HDIM + ks;
      float4 b0 = *(const float4*)(bp);
      float4 b1 = *(const float4*)(bp + 4);
      short8 s;
      s[0] = (short)f2bf(b0.x); s[1] = (short)f2bf(b0.y);
      s[2] = (short)f2bf(b0.z); s[3] = (short)f2bf(b0.w);
      s[4] = (short)f2bf(b1.x); s[5] = (short)f2bf(b1.y);
      s[6] = (short)f2bf(b1.z); s[7] = (short)f2bf(b1.w);
      bfr[j] = s;
    }

    #pragma unroll
    for (int i = 0; i < 4; i++)
      #pragma unroll
      for (int j = 0; j < 8; j++)
        acc[i][j] = __builtin_amdgcn_mfma_f32_16x16x32_bf16(afr[i], bfr[j], acc[i][j], 0, 0, 0);
  }

  float bias[8];
  #pragma unroll
  for (int j = 0; j < 8; j++) bias[j] = outb[n0 + j * 16 + rA];
  #pragma unroll
  for (int i = 0; i < 4; i++) {
    #pragma unroll
    for (int j = 0; j < 8; j++) {
      #pragma unroll
      for (int r = 0; r < 4; r++) {
        int m = wv * 64 + i * 16 + kg * 4 + r;
        out[(size_t)m * VDIM + n0 + j * 16 + rA] = acc[i][j][r] + bias[j];
      }
    }
  }
}

// ---------------- argmax with fp32 refinement ----------------
__global__ __launch_bounds__(256) void k_argmax(const float* __restrict__ logits,
                                                const float* __restrict__ hseqf,
                                                const float* __restrict__ outw,
                                                const float* __restrict__ outb,
                                                float* __restrict__ outids) {
  const int t = blockIdx.x;
  const int tid = threadIdx.x;
  const float* row = logits + (size_t)t * VDIM;

  float mx = -3.4e38f;
  for (int v = tid; v < VDIM; v += 256) mx = fmaxf(mx, row[v]);
  __shared__ float sm[256];
  sm[tid] = mx;
  __syncthreads();
  for (int s = 128; s > 0; s >>= 1) {
    if (tid < s) sm[tid] = fmaxf(sm[tid], sm[tid + s]);
    __syncthreads();
  }
  const float bmax = sm[0];
  __syncthreads();

  __shared__ int cand[64];
  __shared__ int cnt;
  if (tid == 0) cnt = 0;
  __syncthreads();
  const float cut = bmax - 0.25f;
  for (int v = tid; v < VDIM; v += 256) {
    if (row[v] >= cut) {
      int p = atomicAdd(&cnt, 1);
      if (p < 64) cand[p] = v;
    }
  }
  __syncthreads();
  int n = cnt < 64 ? cnt : 64;

  __shared__ float cval[64];
  if (tid < n) {
    int v = cand[tid];
    const float* w = outw + (size_t)v * HDIM;
    const float* h = hseqf + (size_t)t * HDIM;
    float s0 = 0.f, s1 = 0.f, s2 = 0.f, s3 = 0.f;
    for (int k = 0; k < HDIM; k += 4) {
      float4 wf = *(const float4*)(w + k);
      float4 hf = *(const float4*)(h + k);
      s0 += wf.x * hf.x; s1 += wf.y * hf.y; s2 += wf.z * hf.z; s3 += wf.w * hf.w;
    }
    cval[tid] = (s0 + s1) + (s2 + s3) + outb[v];
  }
  __syncthreads();
  if (tid == 0) {
    float best = -3.4e38f; int bi = 0x7FFFFFFF;
    for (int i = 0; i < n; i++) {
      float v = cval[i]; int id = cand[i];
      if (v > best || (v == best && id < bi)) { best = v; bi = id; }
    }
    outids[t] = (float)bi;
  }
}

// ---------------- launch ----------------
extern "C" void kernel_launch(void* const* d_in, const int* in_sizes, int n_in,
                              void* d_out, int out_size, void* d_ws, size_t ws_size,
                              hipStream_t stream) {
  (void)in_sizes; (void)n_in; (void)out_size; (void)ws_size;
  const float* enc    = (const float*)d_in[0];
  const int*   tokens = (const int*)d_in[1];
  const float* emb    = (const float*)d_in[2];
  const float* wzx_w  = (const float*)d_in[3];
  const float* wzx_b  = (const float*)d_in[4];
  const float* wrx_w  = (const float*)d_in[5];
  const float* wrx_b  = (const float*)d_in[6];
  const float* whx_w  = (const float*)d_in[7];
  const float* whx_b  = (const float*)d_in[8];
  const float* wzh_w  = (const float*)d_in[9];
  const float* wzh_b  = (const float*)d_in[10];
  const float* wrh_w  = (const float*)d_in[11];
  const float* wrh_b  = (const float*)d_in[12];
  const float* whh_w  = (const float*)d_in[13];
  const float* whh_b  = (const float*)d_in[14];
  const float* out_w  = (const float*)d_in[15];
  const float* out_b  = (const float*)d_in[16];
  float* ws  = (float*)d_ws;
  float* out = (float*)d_out;

  k_init<<<dim3(T_STEPS + 2), dim3(256), 0, stream>>>(enc, ws);
  k_xproj<<<dim3(192), dim3(256), 0, stream>>>(tokens, emb, wzx_w, wrx_w, whx_w,
                                               wzx_b, wzh_b, wrx_b, wrh_b, whx_b, whh_b, ws);
  k_recur<<<dim3(RG), dim3(256), 0, stream>>>(wzh_w, wrh_w, whh_w, ws);
  k_gemm<<<dim3(VDIM / 128), dim3(256), 0, stream>>>((const unsigned short*)(ws + WS_HSEQB),
                                                     out_w, out_b, out);
  k_argmax<<<dim3(T_STEPS), dim3(256), 0, stream>>>(out, ws + WS_HSEQ, out_w, out_b,
                                                    out + (size_t)T_STEPS * VDIM);
}

// Round 6
// 2400.950 us; speedup vs baseline: 1.2114x; 1.2114x over previous
//
#include <hip/hip_runtime.h>
#include <hip/hip_bf16.h>
#include <math.h>

// ---------------- problem constants ----------------
constexpr int T_STEPS = 256;
constexpr int HDIM    = 1024;
constexpr int EDIM    = 512;
constexpr int VDIM    = 32000;

#define RG     128          // recurrence workgroups (spread over chip, 1/CU)
#define RROWS  8            // rows owned per WG

// ---------------- ws layout (float offsets) ----------------
// Overlays (proven by publish-chain ordering): hseq fp32 over BZ, hseq bf16 over BR.
constexpr size_t WS_BZ     = 0;                                   // [T][H]
constexpr size_t WS_BR     = WS_BZ + (size_t)T_STEPS * HDIM;      // [T][H]
constexpr size_t WS_A      = WS_BR + (size_t)T_STEPS * HDIM;      // [T][H]
constexpr size_t WS_HPACK  = WS_A  + (size_t)T_STEPS * HDIM;      // ull[(T+1)][H]: (tag<<32)|bits
constexpr size_t WS_RHPACK = WS_HPACK + (size_t)2 * (T_STEPS + 1) * HDIM; // ull[H]
constexpr size_t WS_FLAGS  = WS_RHPACK + (size_t)2 * HDIM;        // int[RG]=flagH, int[RG]=flagRH
constexpr size_t WS_HSEQ   = WS_BZ;                               // fp32 overlay
constexpr size_t WS_HSEQB  = WS_BR;                               // bf16 overlay (ushort*)

typedef __attribute__((ext_vector_type(8))) short short8;
typedef __attribute__((ext_vector_type(4))) float f32x4;

__device__ __forceinline__ float sigmoidf_(float x) { return 1.0f / (1.0f + __expf(-x)); }

__device__ __forceinline__ unsigned long long pack_tv(int tag, float v) {
  return ((unsigned long long)(unsigned)tag << 32) | (unsigned long long)__float_as_uint(v);
}

__device__ __forceinline__ unsigned short f2bf(float f) {   // RNE fp32 -> bf16 bits
  unsigned u = __float_as_uint(f);
  return (unsigned short)((u + 0x7FFFu + ((u >> 16) & 1u)) >> 16);
}

// ---------------- init: clear tags+flags (ws NOT re-poisoned between replays), pack h0 ----------------
__global__ __launch_bounds__(256) void k_init(const float* __restrict__ enc, float* __restrict__ ws) {
  unsigned long long* hpack  = (unsigned long long*)(ws + WS_HPACK);
  unsigned long long* rhpack = (unsigned long long*)(ws + WS_RHPACK);
  int* flagH  = (int*)(ws + WS_FLAGS);
  int* flagRH = flagH + RG;
  const int b = blockIdx.x, tid = threadIdx.x;
  if (b == 0) {
    for (int i = tid; i < HDIM; i += 256) hpack[i] = pack_tv(1, enc[i]);
  } else if (b <= T_STEPS) {
    unsigned long long* row = hpack + (size_t)b * HDIM;
    for (int i = tid; i < HDIM; i += 256) row[i] = 0ULL;
  } else {
    for (int i = tid; i < HDIM; i += 256) rhpack[i] = 0ULL;
    if (tid < RG) { flagH[tid] = 1; flagRH[tid] = 0; }   // h0 ready
  }
}

// ---------------- batched e-projections: Bz/Br/A for all t ----------------
__global__ __launch_bounds__(256) void k_xproj(
    const int* __restrict__ tokens, const float* __restrict__ emb,
    const float* __restrict__ wzx, const float* __restrict__ wrx, const float* __restrict__ whx,
    const float* __restrict__ bzx, const float* __restrict__ bzh,
    const float* __restrict__ brx, const float* __restrict__ brh,
    const float* __restrict__ bhx, const float* __restrict__ bhh,
    float* __restrict__ ws) {
  __shared__ __align__(16) float es[16][EDIM];   // 32 KiB
  const int b   = blockIdx.x;
  const int t0  = (b & 15) * 16;
  const int c   = b >> 4;                 // 0..11
  const int tid = threadIdx.x;

  {
    int row = tid >> 4;
    int kc  = (tid & 15) * 32;
    int tok = tokens[t0 + row];
    const float4* ep = (const float4*)(emb + (size_t)tok * EDIM + kc);
    float4* dst = (float4*)&es[row][kc];
    #pragma unroll
    for (int q = 0; q < 8; q++) dst[q] = ep[q];
  }
  __syncthreads();

  const int mat = c >> 2;
  const int j   = (c & 3) * 256 + tid;
  const float* W; const float* b1; const float* b2; float* Xout;
  if (mat == 0)      { W = wzx; b1 = bzx; b2 = bzh; Xout = ws + WS_BZ; }
  else if (mat == 1) { W = wrx; b1 = brx; b2 = brh; Xout = ws + WS_BR; }
  else               { W = whx; b1 = bhx; b2 = bhh; Xout = ws + WS_A;  }

  const float4* wp = (const float4*)(W + (size_t)j * EDIM);
  const float bias = b1[j] + b2[j];
  float acc[16];
  #pragma unroll
  for (int tt = 0; tt < 16; tt++) acc[tt] = 0.0f;

  for (int k4 = 0; k4 < EDIM / 4; k4++) {
    float4 w = wp[k4];
    #pragma unroll
    for (int tt = 0; tt < 16; tt++) {
      float4 e4 = *(const float4*)&es[tt][k4 * 4];
      acc[tt] += w.x * e4.x + w.y * e4.y + w.z * e4.z + w.w * e4.w;
    }
  }
  #pragma unroll
  for (int tt = 0; tt < 16; tt++)
    Xout[(size_t)(t0 + tt) * HDIM + j] = acc[tt] + bias;
}

// ---------------- persistent GRU recurrence ----------------
// Round-3 structure + low-contention wait: poll a per-producer FLAG word (wave's 64 polls
// = ONE cache line) as a hint, then tag-verify the 4 data words (normally 1 iteration).
// Flags carry no ordering (no fences); the data tags self-validate.
__global__ __launch_bounds__(256) void k_recur(
    const float* __restrict__ wzh, const float* __restrict__ wrh, const float* __restrict__ whh,
    float* __restrict__ ws) {
  const int g    = blockIdx.x;
  const int tid  = threadIdx.x;
  const int lane = tid & 63;
  const int wv   = tid >> 6;
  const float* Bz = ws + WS_BZ;
  const float* Br = ws + WS_BR;
  const float* Aa = ws + WS_A;
  float* hseq = ws + WS_HSEQ;
  unsigned short* hseqb = (unsigned short*)(ws + WS_HSEQB);
  unsigned long long* hpack  = (unsigned long long*)(ws + WS_HPACK);
  unsigned long long* rhpack = (unsigned long long*)(ws + WS_RHPACK);
  int* flagH  = (int*)(ws + WS_FLAGS);
  int* flagRH = flagH + RG;

  const int j0 = 4 * tid;          // this thread's h-slice [j0, j0+4) — single producer WG
  const int r0 = g * RROWS;        // this WG's row base
  const int pollidx = tid >> 1;    // producer WG of words [j0, j0+4)

  // register-resident weights: 3 x 8 rows x 4 cols = 96 floats
  float4 wz[RROWS], wr[RROWS], wh[RROWS];
  #pragma unroll
  for (int k = 0; k < RROWS; k++) {
    wz[k] = *(const float4*)(wzh + (size_t)(r0 + k) * HDIM + j0);
    wr[k] = *(const float4*)(wrh + (size_t)(r0 + k) * HDIM + j0);
    wh[k] = *(const float4*)(whh + (size_t)(r0 + k) * HDIM + j0);
  }

  __shared__ float redA[4][2 * RROWS];   // round A (z | r); separate from round B
  __shared__ float redB[4][RROWS];
  __shared__ float zs[RROWS];
  __shared__ float hloc[RROWS];
  if (tid < RROWS)
    hloc[tid] = __uint_as_float((unsigned)hpack[r0 + tid]);  // h0, written by k_init
  __syncthreads();

  for (int t = 0; t < T_STEPS; t++) {
    float bz_pre = 0.0f, br_pre = 0.0f, a_pre = 0.0f;
    if (tid < RROWS) {
      bz_pre = Bz[(size_t)t * HDIM + r0 + tid];
      a_pre  = Aa[(size_t)t * HDIM + r0 + tid];
    } else if (tid < 2 * RROWS) {
      br_pre = Br[(size_t)t * HDIM + r0 + (tid - RROWS)];
    }
    const unsigned long long ex = (unsigned long long)(unsigned)(t + 1);
    const int exf = t + 1;

    // ================= round A: z, r, publish r*h =================
    float hv0, hv1, hv2, hv3;
    {
      // 1) low-contention hint: poll producer's flag (wave = one 128B line)
      int it = 0;
      for (;;) {
        int f = __hip_atomic_load(&flagH[pollidx], __ATOMIC_RELAXED, __HIP_MEMORY_SCOPE_AGENT);
        if (f >= exf) break;
        if (++it > (1 << 20)) break;
        __builtin_amdgcn_s_sleep(1);
      }
      // 2) tag-verify data (normally ready; flag may slightly outrun data stores)
      const unsigned long long* hp = hpack + (size_t)t * HDIM + j0;
      unsigned long long w0, w1, w2, w3;
      for (;;) {
        w0 = __hip_atomic_load(hp + 0, __ATOMIC_RELAXED, __HIP_MEMORY_SCOPE_AGENT);
        w1 = __hip_atomic_load(hp + 1, __ATOMIC_RELAXED, __HIP_MEMORY_SCOPE_AGENT);
        w2 = __hip_atomic_load(hp + 2, __ATOMIC_RELAXED, __HIP_MEMORY_SCOPE_AGENT);
        w3 = __hip_atomic_load(hp + 3, __ATOMIC_RELAXED, __HIP_MEMORY_SCOPE_AGENT);
        if (((w0 >> 32) == ex) & ((w1 >> 32) == ex) & ((w2 >> 32) == ex) & ((w3 >> 32) == ex)) break;
        if (++it > (1 << 20)) break;
        __builtin_amdgcn_s_sleep(1);
      }
      hv0 = __uint_as_float((unsigned)w0);
      hv1 = __uint_as_float((unsigned)w1);
      hv2 = __uint_as_float((unsigned)w2);
      hv3 = __uint_as_float((unsigned)w3);
    }

    float pz[RROWS], pr[RROWS];
    #pragma unroll
    for (int k = 0; k < RROWS; k++) {
      pz[k] = wz[k].x * hv0 + wz[k].y * hv1 + wz[k].z * hv2 + wz[k].w * hv3;
      pr[k] = wr[k].x * hv0 + wr[k].y * hv1 + wr[k].z * hv2 + wr[k].w * hv3;
    }
    #pragma unroll
    for (int m = 32; m >= 1; m >>= 1) {
      #pragma unroll
      for (int k = 0; k < RROWS; k++) {
        pz[k] += __shfl_xor(pz[k], m);
        pr[k] += __shfl_xor(pr[k], m);
      }
    }
    if (lane == 0) {
      #pragma unroll
      for (int k = 0; k < RROWS; k++) { redA[wv][k] = pz[k]; redA[wv][RROWS + k] = pr[k]; }
    }
    __syncthreads();
    if (tid < RROWS) {
      float u = redA[0][tid] + redA[1][tid] + redA[2][tid] + redA[3][tid];
      zs[tid] = sigmoidf_(bz_pre + u);
    } else if (tid < 2 * RROWS) {
      int k = tid - RROWS;
      float u = redA[0][tid] + redA[1][tid] + redA[2][tid] + redA[3][tid];
      float r = sigmoidf_(br_pre + u);
      float rh = r * hloc[k];
      __hip_atomic_store(&rhpack[r0 + k], pack_tv(t + 1, rh),
                         __ATOMIC_RELAXED, __HIP_MEMORY_SCOPE_AGENT);
    }
    // flag hint: wave 0 is lockstep, so tid 0 reaches here only after tids 8..15 issued stores
    if (tid == 0)
      __hip_atomic_store(&flagRH[g], exf, __ATOMIC_RELAXED, __HIP_MEMORY_SCOPE_AGENT);

    // ================= round B: v = whh@(r*h), h_new =================
    float rv0, rv1, rv2, rv3;
    {
      int it = 0;
      for (;;) {
        int f = __hip_atomic_load(&flagRH[pollidx], __ATOMIC_RELAXED, __HIP_MEMORY_SCOPE_AGENT);
        if (f >= exf) break;
        if (++it > (1 << 20)) break;
        __builtin_amdgcn_s_sleep(1);
      }
      const unsigned long long* rp = rhpack + j0;
      unsigned long long w0, w1, w2, w3;
      for (;;) {
        w0 = __hip_atomic_load(rp + 0, __ATOMIC_RELAXED, __HIP_MEMORY_SCOPE_AGENT);
        w1 = __hip_atomic_load(rp + 1, __ATOMIC_RELAXED, __HIP_MEMORY_SCOPE_AGENT);
        w2 = __hip_atomic_load(rp + 2, __ATOMIC_RELAXED, __HIP_MEMORY_SCOPE_AGENT);
        w3 = __hip_atomic_load(rp + 3, __ATOMIC_RELAXED, __HIP_MEMORY_SCOPE_AGENT);
        if (((w0 >> 32) == ex) & ((w1 >> 32) == ex) & ((w2 >> 32) == ex) & ((w3 >> 32) == ex)) break;
        if (++it > (1 << 20)) break;
        __builtin_amdgcn_s_sleep(1);
      }
      rv0 = __uint_as_float((unsigned)w0);
      rv1 = __uint_as_float((unsigned)w1);
      rv2 = __uint_as_float((unsigned)w2);
      rv3 = __uint_as_float((unsigned)w3);
    }

    float ph[RROWS];
    #pragma unroll
    for (int k = 0; k < RROWS; k++)
      ph[k] = wh[k].x * rv0 + wh[k].y * rv1 + wh[k].z * rv2 + wh[k].w * rv3;
    #pragma unroll
    for (int m = 32; m >= 1; m >>= 1) {
      #pragma unroll
      for (int k = 0; k < RROWS; k++) ph[k] += __shfl_xor(ph[k], m);
    }
    if (lane == 0) {
      #pragma unroll
      for (int k = 0; k < RROWS; k++) redB[wv][k] = ph[k];
    }
    __syncthreads();
    if (tid < RROWS) {
      float v  = redB[0][tid] + redB[1][tid] + redB[2][tid] + redB[3][tid];
      float z  = zs[tid];
      float hk = hloc[tid];
      float hp_ = tanhf(a_pre + v);
      float hn = (1.0f - z) * hk + z * hp_;
      hloc[tid] = hn;
      __hip_atomic_store(&hpack[(size_t)(t + 1) * HDIM + r0 + tid], pack_tv(t + 2, hn),
                         __ATOMIC_RELAXED, __HIP_MEMORY_SCOPE_AGENT);
      hseq[(size_t)t * HDIM + r0 + tid] = hn;               // fp32 (refine)
      hseqb[(size_t)t * HDIM + r0 + tid] = f2bf(hn);        // bf16 (GEMM A)
    }
    if (tid == 0)
      __hip_atomic_store(&flagH[g], exf + 1, __ATOMIC_RELAXED, __HIP_MEMORY_SCOPE_AGENT);
  }
}

// ---------------- logits GEMM (bf16 MFMA): [256,1024] @ out_w[32000,1024]^T + out_b ----------------
__global__ __launch_bounds__(256) void k_gemm(
    const unsigned short* __restrict__ Abf, const float* __restrict__ outw,
    const float* __restrict__ outb, float* __restrict__ out) {
  const int tid  = threadIdx.x;
  const int lane = tid & 63;
  const int wv   = tid >> 6;
  const int n0   = blockIdx.x * 128;
  const int rA   = lane & 15;
  const int kg   = lane >> 4;

  f32x4 acc[4][8];
  #pragma unroll
  for (int i = 0; i < 4; i++)
    #pragma unroll
    for (int j = 0; j < 8; j++) acc[i][j] = (f32x4){0.f, 0.f, 0.f, 0.f};

  const int mbase = wv * 64 + rA;

  for (int k0 = 0; k0 < HDIM; k0 += 32) {
    const int ks = k0 + kg * 8;
    short8 afr[4];
    #pragma unroll
    for (int i = 0; i < 4; i++)
      afr[i] = *(const short8*)(Abf + (size_t)(mbase + i * 16) * HDIM + ks);

    short8 bfr[8];
    #pragma unroll
    for (int j = 0; j < 8; j++) {
      const float* bp = outw + (size_t)(n0 + j * 16 + rA) * HDIM + ks;
      float4 b0 = *(const float4*)(bp);
      float4 b1 = *(const float4*)(bp + 4);
      short8 s;
      s[0] = (short)f2bf(b0.x); s[1] = (short)f2bf(b0.y);
      s[2] = (short)f2bf(b0.z); s[3] = (short)f2bf(b0.w);
      s[4] = (short)f2bf(b1.x); s[5] = (short)f2bf(b1.y);
      s[6] = (short)f2bf(b1.z); s[7] = (short)f2bf(b1.w);
      bfr[j] = s;
    }

    #pragma unroll
    for (int i = 0; i < 4; i++)
      #pragma unroll
      for (int j = 0; j < 8; j++)
        acc[i][j] = __builtin_amdgcn_mfma_f32_16x16x32_bf16(afr[i], bfr[j], acc[i][j], 0, 0, 0);
  }

  float bias[8];
  #pragma unroll
  for (int j = 0; j < 8; j++) bias[j] = outb[n0 + j * 16 + rA];
  #pragma unroll
  for (int i = 0; i < 4; i++) {
    #pragma unroll
    for (int j = 0; j < 8; j++) {
      #pragma unroll
      for (int r = 0; r < 4; r++) {
        int m = wv * 64 + i * 16 + kg * 4 + r;
        out[(size_t)m * VDIM + n0 + j * 16 + rA] = acc[i][j][r] + bias[j];
      }
    }
  }
}

// ---------------- argmax with fp32 refinement ----------------
__global__ __launch_bounds__(256) void k_argmax(const float* __restrict__ logits,
                                                const float* __restrict__ hseqf,
                                                const float* __restrict__ outw,
                                                const float* __restrict__ outb,
                                                float* __restrict__ outids) {
  const int t = blockIdx.x;
  const int tid = threadIdx.x;
  const float* row = logits + (size_t)t * VDIM;

  float mx = -3.4e38f;
  for (int v = tid; v < VDIM; v += 256) mx = fmaxf(mx, row[v]);
  __shared__ float sm[256];
  sm[tid] = mx;
  __syncthreads();
  for (int s = 128; s > 0; s >>= 1) {
    if (tid < s) sm[tid] = fmaxf(sm[tid], sm[tid + s]);
    __syncthreads();
  }
  const float bmax = sm[0];
  __syncthreads();

  __shared__ int cand[64];
  __shared__ int cnt;
  if (tid == 0) cnt = 0;
  __syncthreads();
  const float cut = bmax - 0.25f;
  for (int v = tid; v < VDIM; v += 256) {
    if (row[v] >= cut) {
      int p = atomicAdd(&cnt, 1);
      if (p < 64) cand[p] = v;
    }
  }
  __syncthreads();
  int n = cnt < 64 ? cnt : 64;

  __shared__ float cval[64];
  if (tid < n) {
    int v = cand[tid];
    const float* w = outw + (size_t)v * HDIM;
    const float* h = hseqf + (size_t)t * HDIM;
    float s0 = 0.f, s1 = 0.f, s2 = 0.f, s3 = 0.f;
    for (int k = 0; k < HDIM; k += 4) {
      float4 wf = *(const float4*)(w + k);
      float4 hf = *(const float4*)(h + k);
      s0 += wf.x * hf.x; s1 += wf.y * hf.y; s2 += wf.z * hf.z; s3 += wf.w * hf.w;
    }
    cval[tid] = (s0 + s1) + (s2 + s3) + outb[v];
  }
  __syncthreads();
  if (tid == 0) {
    float best = -3.4e38f; int bi = 0x7FFFFFFF;
    for (int i = 0; i < n; i++) {
      float v = cval[i]; int id = cand[i];
      if (v > best || (v == best && id < bi)) { best = v; bi = id; }
    }
    outids[t] = (float)bi;
  }
}

// ---------------- launch ----------------
extern "C" void kernel_launch(void* const* d_in, const int* in_sizes, int n_in,
                              void* d_out, int out_size, void* d_ws, size_t ws_size,
                              hipStream_t stream) {
  (void)in_sizes; (void)n_in; (void)out_size; (void)ws_size;
  const float* enc    = (const float*)d_in[0];
  const int*   tokens = (const int*)d_in[1];
  const float* emb    = (const float*)d_in[2];
  const float* wzx_w  = (const float*)d_in[3];
  const float* wzx_b  = (const float*)d_in[4];
  const float* wrx_w  = (const float*)d_in[5];
  const float* wrx_b  = (const float*)d_in[6];
  const float* whx_w  = (const float*)d_in[7];
  const float* whx_b  = (const float*)d_in[8];
  const float* wzh_w  = (const float*)d_in[9];
  const float* wzh_b  = (const float*)d_in[10];
  const float* wrh_w  = (const float*)d_in[11];
  const float* wrh_b  = (const float*)d_in[12];
  const float* whh_w  = (const float*)d_in[13];
  const float* whh_b  = (const float*)d_in[14];
  const float* out_w  = (const float*)d_in[15];
  const float* out_b  = (const float*)d_in[16];
  float* ws  = (float*)d_ws;
  float* out = (float*)d_out;

  k_init<<<dim3(T_STEPS + 2), dim3(256), 0, stream>>>(enc, ws);
  k_xproj<<<dim3(192), dim3(256), 0, stream>>>(tokens, emb, wzx_w, wrx_w, whx_w,
                                               wzx_b, wzh_b, wrx_b, wrh_b, whx_b, whh_b, ws);
  k_recur<<<dim3(RG), dim3(256), 0, stream>>>(wzh_w, wrh_w, whh_w, ws);
  k_gemm<<<dim3(VDIM / 128), dim3(256), 0, stream>>>((const unsigned short*)(ws + WS_HSEQB),
                                                     out_w, out_b, out);
  k_argmax<<<dim3(T_STEPS), dim3(256), 0, stream>>>(out, ws + WS_HSEQ, out_w, out_b,
                                                    out + (size_t)T_STEPS * VDIM);
}

// Round 7
// 1452.473 us; speedup vs baseline: 2.0025x; 1.6530x over previous
//
#include <hip/hip_runtime.h>
#include <hip/hip_bf16.h>
#include <math.h>

// ---------------- problem constants ----------------
constexpr int T_STEPS = 256;
constexpr int HDIM    = 1024;
constexpr int EDIM    = 512;
constexpr int VDIM    = 32000;

#define RG     128          // recurrence workgroups (spread over chip, 1/CU)
#define RROWS  8            // rows owned per WG

// ---------------- ws layout (float offsets) ----------------
// Overlays (proven by publish-chain ordering): hseq fp32 over BZ, hseq bf16 over BR.
constexpr size_t WS_BZ     = 0;                                   // [T][H]
constexpr size_t WS_BR     = WS_BZ + (size_t)T_STEPS * HDIM;      // [T][H]
constexpr size_t WS_A      = WS_BR + (size_t)T_STEPS * HDIM;      // [T][H]
constexpr size_t WS_HPACK  = WS_A  + (size_t)T_STEPS * HDIM;      // ull[(T+1)][H]: (tag<<32)|bits
constexpr size_t WS_RHPACK = WS_HPACK + (size_t)2 * (T_STEPS + 1) * HDIM; // ull[H]
constexpr size_t WS_HSEQ   = WS_BZ;                               // fp32 overlay
constexpr size_t WS_HSEQB  = WS_BR;                               // bf16 overlay (ushort*)

typedef __attribute__((ext_vector_type(8))) short short8;
typedef __attribute__((ext_vector_type(4))) float f32x4;

__device__ __forceinline__ float sigmoidf_(float x) { return 1.0f / (1.0f + __expf(-x)); }

__device__ __forceinline__ unsigned long long pack_tv(int tag, float v) {
  return ((unsigned long long)(unsigned)tag << 32) | (unsigned long long)__float_as_uint(v);
}

__device__ __forceinline__ unsigned short f2bf(float f) {   // RNE fp32 -> bf16 bits (manual)
  unsigned u = __float_as_uint(f);
  return (unsigned short)((u + 0x7FFFu + ((u >> 16) & 1u)) >> 16);
}

__device__ __forceinline__ unsigned short f2bf_fast(float f) {  // compiler-fusable RNE cast
  __hip_bfloat16 b = __float2bfloat16(f);
  return *reinterpret_cast<unsigned short*>(&b);
}

// RMW publish: atomic exchange executes AT the coherence point (IC) — cannot linger
// in store/write-combine buffers the way a relaxed store can. Result ignored.
__device__ __forceinline__ void publish(unsigned long long* p, unsigned long long v) {
  (void)__hip_atomic_exchange(p, v, __ATOMIC_RELAXED, __HIP_MEMORY_SCOPE_AGENT);
}

// ---------------- init: clear tags (ws NOT re-poisoned between replays), pack h0 ----------------
__global__ __launch_bounds__(256) void k_init(const float* __restrict__ enc, float* __restrict__ ws) {
  unsigned long long* hpack  = (unsigned long long*)(ws + WS_HPACK);
  unsigned long long* rhpack = (unsigned long long*)(ws + WS_RHPACK);
  const int b = blockIdx.x, tid = threadIdx.x;
  if (b == 0) {
    for (int i = tid; i < HDIM; i += 256) hpack[i] = pack_tv(1, enc[i]);
  } else if (b <= T_STEPS) {
    unsigned long long* row = hpack + (size_t)b * HDIM;
    for (int i = tid; i < HDIM; i += 256) row[i] = 0ULL;
  } else {
    for (int i = tid; i < HDIM; i += 256) rhpack[i] = 0ULL;
  }
}

// ---------------- batched e-projections: Bz/Br/A for all t ----------------
__global__ __launch_bounds__(256) void k_xproj(
    const int* __restrict__ tokens, const float* __restrict__ emb,
    const float* __restrict__ wzx, const float* __restrict__ wrx, const float* __restrict__ whx,
    const float* __restrict__ bzx, const float* __restrict__ bzh,
    const float* __restrict__ brx, const float* __restrict__ brh,
    const float* __restrict__ bhx, const float* __restrict__ bhh,
    float* __restrict__ ws) {
  __shared__ __align__(16) float es[16][EDIM];   // 32 KiB
  const int b   = blockIdx.x;
  const int t0  = (b & 15) * 16;
  const int c   = b >> 4;                 // 0..11
  const int tid = threadIdx.x;

  {
    int row = tid >> 4;
    int kc  = (tid & 15) * 32;
    int tok = tokens[t0 + row];
    const float4* ep = (const float4*)(emb + (size_t)tok * EDIM + kc);
    float4* dst = (float4*)&es[row][kc];
    #pragma unroll
    for (int q = 0; q < 8; q++) dst[q] = ep[q];
  }
  __syncthreads();

  const int mat = c >> 2;
  const int j   = (c & 3) * 256 + tid;
  const float* W; const float* b1; const float* b2; float* Xout;
  if (mat == 0)      { W = wzx; b1 = bzx; b2 = bzh; Xout = ws + WS_BZ; }
  else if (mat == 1) { W = wrx; b1 = brx; b2 = brh; Xout = ws + WS_BR; }
  else               { W = whx; b1 = bhx; b2 = bhh; Xout = ws + WS_A;  }

  const float4* wp = (const float4*)(W + (size_t)j * EDIM);
  const float bias = b1[j] + b2[j];
  float acc[16];
  #pragma unroll
  for (int tt = 0; tt < 16; tt++) acc[tt] = 0.0f;

  for (int k4 = 0; k4 < EDIM / 4; k4++) {
    float4 w = wp[k4];
    #pragma unroll
    for (int tt = 0; tt < 16; tt++) {
      float4 e4 = *(const float4*)&es[tt][k4 * 4];
      acc[tt] += w.x * e4.x + w.y * e4.y + w.z * e4.z + w.w * e4.w;
    }
  }
  #pragma unroll
  for (int tt = 0; tt < 16; tt++)
    Xout[(size_t)(t0 + tt) * HDIM + j] = acc[tt] + bias;
}

// ---------------- persistent GRU recurrence (r3 structure; publishes via atomic RMW) ----------------
__global__ __launch_bounds__(256) void k_recur(
    const float* __restrict__ wzh, const float* __restrict__ wrh, const float* __restrict__ whh,
    float* __restrict__ ws) {
  const int g    = blockIdx.x;
  const int tid  = threadIdx.x;
  const int lane = tid & 63;
  const int wv   = tid >> 6;
  const float* Bz = ws + WS_BZ;
  const float* Br = ws + WS_BR;
  const float* Aa = ws + WS_A;
  float* hseq = ws + WS_HSEQ;
  unsigned short* hseqb = (unsigned short*)(ws + WS_HSEQB);
  unsigned long long* hpack  = (unsigned long long*)(ws + WS_HPACK);
  unsigned long long* rhpack = (unsigned long long*)(ws + WS_RHPACK);

  const int j0 = 4 * tid;          // this thread's h-slice [j0, j0+4) — single producer WG
  const int r0 = g * RROWS;        // this WG's row base

  // register-resident weights: 3 x 8 rows x 4 cols = 96 floats
  float4 wz[RROWS], wr[RROWS], wh[RROWS];
  #pragma unroll
  for (int k = 0; k < RROWS; k++) {
    wz[k] = *(const float4*)(wzh + (size_t)(r0 + k) * HDIM + j0);
    wr[k] = *(const float4*)(wrh + (size_t)(r0 + k) * HDIM + j0);
    wh[k] = *(const float4*)(whh + (size_t)(r0 + k) * HDIM + j0);
  }

  __shared__ float redA[4][2 * RROWS];   // round A (z | r); separate from round B
  __shared__ float redB[4][RROWS];
  __shared__ float zs[RROWS];
  __shared__ float hloc[RROWS];
  if (tid < RROWS)
    hloc[tid] = __uint_as_float((unsigned)hpack[r0 + tid]);  // h0, written by k_init
  __syncthreads();

  for (int t = 0; t < T_STEPS; t++) {
    float bz_pre = 0.0f, br_pre = 0.0f, a_pre = 0.0f;
    if (tid < RROWS) {
      bz_pre = Bz[(size_t)t * HDIM + r0 + tid];
      a_pre  = Aa[(size_t)t * HDIM + r0 + tid];
    } else if (tid < 2 * RROWS) {
      br_pre = Br[(size_t)t * HDIM + r0 + (tid - RROWS)];
    }
    const unsigned long long ex = (unsigned long long)(unsigned)(t + 1);

    // ================= round A: z, r, publish r*h =================
    float hv0, hv1, hv2, hv3;
    {
      const unsigned long long* hp = hpack + (size_t)t * HDIM + j0;
      unsigned long long w0, w1, w2, w3;
      int it = 0;
      for (;;) {   // sentinel poll: word 0 only
        w0 = __hip_atomic_load(hp + 0, __ATOMIC_RELAXED, __HIP_MEMORY_SCOPE_AGENT);
        if ((w0 >> 32) == ex) break;
        if (++it > (1 << 20)) break;
        __builtin_amdgcn_s_sleep(2);
      }
      for (;;) {   // remaining 3 words: same producer wave-store, nearly always ready
        w1 = __hip_atomic_load(hp + 1, __ATOMIC_RELAXED, __HIP_MEMORY_SCOPE_AGENT);
        w2 = __hip_atomic_load(hp + 2, __ATOMIC_RELAXED, __HIP_MEMORY_SCOPE_AGENT);
        w3 = __hip_atomic_load(hp + 3, __ATOMIC_RELAXED, __HIP_MEMORY_SCOPE_AGENT);
        if (((w1 >> 32) == ex) & ((w2 >> 32) == ex) & ((w3 >> 32) == ex)) break;
        if (++it > (1 << 20)) break;
        __builtin_amdgcn_s_sleep(1);
      }
      hv0 = __uint_as_float((unsigned)w0);
      hv1 = __uint_as_float((unsigned)w1);
      hv2 = __uint_as_float((unsigned)w2);
      hv3 = __uint_as_float((unsigned)w3);
    }

    float pz[RROWS], pr[RROWS];
    #pragma unroll
    for (int k = 0; k < RROWS; k++) {
      pz[k] = wz[k].x * hv0 + wz[k].y * hv1 + wz[k].z * hv2 + wz[k].w * hv3;
      pr[k] = wr[k].x * hv0 + wr[k].y * hv1 + wr[k].z * hv2 + wr[k].w * hv3;
    }
    #pragma unroll
    for (int m = 32; m >= 1; m >>= 1) {
      #pragma unroll
      for (int k = 0; k < RROWS; k++) {
        pz[k] += __shfl_xor(pz[k], m);
        pr[k] += __shfl_xor(pr[k], m);
      }
    }
    if (lane == 0) {
      #pragma unroll
      for (int k = 0; k < RROWS; k++) { redA[wv][k] = pz[k]; redA[wv][RROWS + k] = pr[k]; }
    }
    __syncthreads();
    if (tid < RROWS) {
      float u = redA[0][tid] + redA[1][tid] + redA[2][tid] + redA[3][tid];
      zs[tid] = sigmoidf_(bz_pre + u);
    } else if (tid < 2 * RROWS) {
      int k = tid - RROWS;
      float u = redA[0][tid] + redA[1][tid] + redA[2][tid] + redA[3][tid];
      float r = sigmoidf_(br_pre + u);
      float rh = r * hloc[k];
      publish(&rhpack[r0 + k], pack_tv(t + 1, rh));
    }

    // ================= round B: v = whh@(r*h), h_new =================
    float rv0, rv1, rv2, rv3;
    {
      const unsigned long long* rp = rhpack + j0;
      unsigned long long w0, w1, w2, w3;
      int it = 0;
      for (;;) {
        w0 = __hip_atomic_load(rp + 0, __ATOMIC_RELAXED, __HIP_MEMORY_SCOPE_AGENT);
        if ((w0 >> 32) == ex) break;
        if (++it > (1 << 20)) break;
        __builtin_amdgcn_s_sleep(2);
      }
      for (;;) {
        w1 = __hip_atomic_load(rp + 1, __ATOMIC_RELAXED, __HIP_MEMORY_SCOPE_AGENT);
        w2 = __hip_atomic_load(rp + 2, __ATOMIC_RELAXED, __HIP_MEMORY_SCOPE_AGENT);
        w3 = __hip_atomic_load(rp + 3, __ATOMIC_RELAXED, __HIP_MEMORY_SCOPE_AGENT);
        if (((w1 >> 32) == ex) & ((w2 >> 32) == ex) & ((w3 >> 32) == ex)) break;
        if (++it > (1 << 20)) break;
        __builtin_amdgcn_s_sleep(1);
      }
      rv0 = __uint_as_float((unsigned)w0);
      rv1 = __uint_as_float((unsigned)w1);
      rv2 = __uint_as_float((unsigned)w2);
      rv3 = __uint_as_float((unsigned)w3);
    }

    float ph[RROWS];
    #pragma unroll
    for (int k = 0; k < RROWS; k++)
      ph[k] = wh[k].x * rv0 + wh[k].y * rv1 + wh[k].z * rv2 + wh[k].w * rv3;
    #pragma unroll
    for (int m = 32; m >= 1; m >>= 1) {
      #pragma unroll
      for (int k = 0; k < RROWS; k++) ph[k] += __shfl_xor(ph[k], m);
    }
    if (lane == 0) {
      #pragma unroll
      for (int k = 0; k < RROWS; k++) redB[wv][k] = ph[k];
    }
    __syncthreads();
    if (tid < RROWS) {
      float v  = redB[0][tid] + redB[1][tid] + redB[2][tid] + redB[3][tid];
      float z  = zs[tid];
      float hk = hloc[tid];
      float hp_ = tanhf(a_pre + v);
      float hn = (1.0f - z) * hk + z * hp_;
      hloc[tid] = hn;
      publish(&hpack[(size_t)(t + 1) * HDIM + r0 + tid], pack_tv(t + 2, hn));
      hseq[(size_t)t * HDIM + r0 + tid] = hn;               // fp32 (refine)
      hseqb[(size_t)t * HDIM + r0 + tid] = f2bf(hn);        // bf16 (GEMM A)
    }
  }
}

// ---------------- logits GEMM (bf16 MFMA): [256,1024] @ out_w[32000,1024]^T + out_b ----------------
__global__ __launch_bounds__(256) void k_gemm(
    const unsigned short* __restrict__ Abf, const float* __restrict__ outw,
    const float* __restrict__ outb, float* __restrict__ out) {
  const int tid  = threadIdx.x;
  const int lane = tid & 63;
  const int wv   = tid >> 6;
  const int n0   = blockIdx.x * 128;
  const int rA   = lane & 15;
  const int kg   = lane >> 4;

  f32x4 acc[4][8];
  #pragma unroll
  for (int i = 0; i < 4; i++)
    #pragma unroll
    for (int j = 0; j < 8; j++) acc[i][j] = (f32x4){0.f, 0.f, 0.f, 0.f};

  const int mbase = wv * 64 + rA;

  for (int k0 = 0; k0 < HDIM; k0 += 32) {
    const int ks = k0 + kg * 8;
    short8 afr[4];
    #pragma unroll
    for (int i = 0; i < 4; i++)
      afr[i] = *(const short8*)(Abf + (size_t)(mbase + i * 16) * HDIM + ks);

    short8 bfr[8];
    #pragma unroll
    for (int j = 0; j < 8; j++) {
      const float* bp = outw + (size_t)(n0 + j * 16 + rA) * HDIM + ks;
      float4 b0 = *(const float4*)(bp);
      float4 b1 = *(const float4*)(bp + 4);
      short8 s;
      s[0] = (short)f2bf_fast(b0.x); s[1] = (short)f2bf_fast(b0.y);
      s[2] = (short)f2bf_fast(b0.z); s[3] = (short)f2bf_fast(b0.w);
      s[4] = (short)f2bf_fast(b1.x); s[5] = (short)f2bf_fast(b1.y);
      s[6] = (short)f2bf_fast(b1.z); s[7] = (short)f2bf_fast(b1.w);
      bfr[j] = s;
    }

    #pragma unroll
    for (int i = 0; i < 4; i++)
      #pragma unroll
      for (int j = 0; j < 8; j++)
        acc[i][j] = __builtin_amdgcn_mfma_f32_16x16x32_bf16(afr[i], bfr[j], acc[i][j], 0, 0, 0);
  }

  float bias[8];
  #pragma unroll
  for (int j = 0; j < 8; j++) bias[j] = outb[n0 + j * 16 + rA];
  #pragma unroll
  for (int i = 0; i < 4; i++) {
    #pragma unroll
    for (int j = 0; j < 8; j++) {
      #pragma unroll
      for (int r = 0; r < 4; r++) {
        int m = wv * 64 + i * 16 + kg * 4 + r;
        out[(size_t)m * VDIM + n0 + j * 16 + rA] = acc[i][j][r] + bias[j];
      }
    }
  }
}

// ---------------- argmax with fp32 refinement ----------------
__global__ __launch_bounds__(256) void k_argmax(const float* __restrict__ logits,
                                                const float* __restrict__ hseqf,
                                                const float* __restrict__ outw,
                                                const float* __restrict__ outb,
                                                float* __restrict__ outids) {
  const int t = blockIdx.x;
  const int tid = threadIdx.x;
  const float* row = logits + (size_t)t * VDIM;

  float mx = -3.4e38f;
  for (int v = tid; v < VDIM; v += 256) mx = fmaxf(mx, row[v]);
  __shared__ float sm[256];
  sm[tid] = mx;
  __syncthreads();
  for (int s = 128; s > 0; s >>= 1) {
    if (tid < s) sm[tid] = fmaxf(sm[tid], sm[tid + s]);
    __syncthreads();
  }
  const float bmax = sm[0];
  __syncthreads();

  __shared__ int cand[64];
  __shared__ int cnt;
  if (tid == 0) cnt = 0;
  __syncthreads();
  const float cut = bmax - 0.25f;
  for (int v = tid; v < VDIM; v += 256) {
    if (row[v] >= cut) {
      int p = atomicAdd(&cnt, 1);
      if (p < 64) cand[p] = v;
    }
  }
  __syncthreads();
  int n = cnt < 64 ? cnt : 64;

  __shared__ float cval[64];
  if (tid < n) {
    int v = cand[tid];
    const float* w = outw + (size_t)v * HDIM;
    const float* h = hseqf + (size_t)t * HDIM;
    float s0 = 0.f, s1 = 0.f, s2 = 0.f, s3 = 0.f;
    for (int k = 0; k < HDIM; k += 4) {
      float4 wf = *(const float4*)(w + k);
      float4 hf = *(const float4*)(h + k);
      s0 += wf.x * hf.x; s1 += wf.y * hf.y; s2 += wf.z * hf.z; s3 += wf.w * hf.w;
    }
    cval[tid] = (s0 + s1) + (s2 + s3) + outb[v];
  }
  __syncthreads();
  if (tid == 0) {
    float best = -3.4e38f; int bi = 0x7FFFFFFF;
    for (int i = 0; i < n; i++) {
      float v = cval[i]; int id = cand[i];
      if (v > best || (v == best && id < bi)) { best = v; bi = id; }
    }
    outids[t] = (float)bi;
  }
}

// ---------------- launch ----------------
extern "C" void kernel_launch(void* const* d_in, const int* in_sizes, int n_in,
                              void* d_out, int out_size, void* d_ws, size_t ws_size,
                              hipStream_t stream) {
  (void)in_sizes; (void)n_in; (void)out_size; (void)ws_size;
  const float* enc    = (const float*)d_in[0];
  const int*   tokens = (const int*)d_in[1];
  const float* emb    = (const float*)d_in[2];
  const float* wzx_w  = (const float*)d_in[3];
  const float* wzx_b  = (const float*)d_in[4];
  const float* wrx_w  = (const float*)d_in[5];
  const float* wrx_b  = (const float*)d_in[6];
  const float* whx_w  = (const float*)d_in[7];
  const float* whx_b  = (const float*)d_in[8];
  const float* wzh_w  = (const float*)d_in[9];
  const float* wzh_b  = (const float*)d_in[10];
  const float* wrh_w  = (const float*)d_in[11];
  const float* wrh_b  = (const float*)d_in[12];
  const float* whh_w  = (const float*)d_in[13];
  const float* whh_b  = (const float*)d_in[14];
  const float* out_w  = (const float*)d_in[15];
  const float* out_b  = (const float*)d_in[16];
  float* ws  = (float*)d_ws;
  float* out = (float*)d_out;

  k_init<<<dim3(T_STEPS + 2), dim3(256), 0, stream>>>(enc, ws);
  k_xproj<<<dim3(192), dim3(256), 0, stream>>>(tokens, emb, wzx_w, wrx_w, whx_w,
                                               wzx_b, wzh_b, wrx_b, wrh_b, whx_b, whh_b, ws);
  k_recur<<<dim3(RG), dim3(256), 0, stream>>>(wzh_w, wrh_w, whh_w, ws);
  k_gemm<<<dim3(VDIM / 128), dim3(256), 0, stream>>>((const unsigned short*)(ws + WS_HSEQB),
                                                     out_w, out_b, out);
  k_argmax<<<dim3(T_STEPS), dim3(256), 0, stream>>>(out, ws + WS_HSEQ, out_w, out_b,
                                                    out + (size_t)T_STEPS * VDIM);
}